// Round 20
// baseline (301.661 us; speedup 1.0000x reference)
//
#include <hip/hip_runtime.h>

#define NN 20000
#define IC 128
#define OC 128
#define NSTEP 32
#define NE 256000
#define KSEL 128000
#define NB 79        // node-range blocks = ceil(NN/256)
#define CH 64        // edge chunks
#define ECH 4000     // NE / CH
#define RND 16       // ceil(ECH/256)
#define HPW 10000    // packed u16 words per chunk histogram
#define CANDCAP 65536
#define NQCOL 704    // 512 beta + 32 p + 128 V + 32 pad

struct SelState {
  unsigned long long prefix;
  unsigned r;       // remaining rank
  unsigned selc;    // unused
  unsigned tiec;    // candidate count
  unsigned done[8]; // block-done counters
};

typedef __attribute__((ext_vector_type(16))) float f16v;

// ---------------------------------------------------------------- init / fold
__global__ void k_init(const float* __restrict__ p_t, const float* __restrict__ lin_w,
                       const float* __restrict__ lin_b,
                       const float* __restrict__ inc_w, const float* __restrict__ inc_b,
                       float* __restrict__ Wq,
                       double* __restrict__ Ud, double* __restrict__ ubd,
                       unsigned* __restrict__ hist, SelState* st) {
  int i = blockIdx.x * blockDim.x + threadIdx.x;
  if (i < 33 * NQCOL) {
    int k4 = i / NQCOL, col = i - k4 * NQCOL;
    float4 o;
    float* ov = (float*)&o;
    for (int jj = 0; jj < 4; ++jj) {
      int k = 4 * k4 + jj;
      float v = 0.f;
      if (col < 512) {
        int t = col >> 4, c = col & 15;
        if (k < 128) v = inc_w[k * 1024 + t * 32 + c];
        else if (k == 128) v = inc_b[t * 32 + c];
      } else if (col < 544) {
        int t = col - 512;
        if (k < 128) {
          float a = 0.f;
          for (int q = 0; q < 16; ++q) a += inc_w[k * 1024 + t * 32 + 16 + q] * p_t[t * 16 + q];
          v = a;
        } else if (k == 128) {
          float a = 0.f;
          for (int q = 0; q < 16; ++q) a += inc_b[t * 32 + 16 + q] * p_t[t * 16 + q];
          v = a;
        }
      } else if (col < 672) {
        int c = col - 544;
        if (k < 128) v = lin_w[k * OC + c];
        else if (k == 128) v = lin_b[c];
      }
      ov[jj] = v;
    }
    ((float4*)Wq)[i] = o;
    return;
  }
  i -= 33 * NQCOL;
  if (i < 17 * IC) {  // f64 folded selection columns: U (16) and q (1)
    int c = i >> 7, k = i & 127;
    double a = 0.0;
    if (c < 16) {
      for (int t = 0; t < NSTEP; ++t) a += (double)inc_w[k * 1024 + t * 32 + c];
    } else {
      for (int t = 0; t < NSTEP; ++t)
        for (int q = 0; q < 16; ++q)
          a += (double)inc_w[k * 1024 + t * 32 + 16 + q] * (double)p_t[t * 16 + q];
    }
    Ud[c * IC + k] = a;
    return;
  }
  i -= 17 * IC;
  if (i < 17) {
    double a = 0.0;
    if (i < 16) {
      for (int t = 0; t < NSTEP; ++t) a += (double)inc_b[t * 32 + i];
    } else {
      for (int t = 0; t < NSTEP; ++t)
        for (int q = 0; q < 16; ++q)
          a += (double)inc_b[t * 32 + 16 + q] * (double)p_t[t * 16 + q];
    }
    ubd[i] = a;
    return;
  }
  i -= 17;
  if (i < 512) { hist[i] = 0u; return; }
  i -= 512;
  if (i == 0) {
    st->prefix = 0ull; st->r = KSEL; st->selc = 0u; st->tiec = 0u;
    for (int p = 0; p < 8; ++p) st->done[p] = 0u;
  }
}

// ---------------- f32 per-node GEMM: uniform weights, half-k4 LDS staging
// grid = dim3(313, 5); block = 4 waves; wave j owns units s*8+j and s*8+j+4
// (s<4 -> both beta units; s==4 -> both V units). LDS halved to 16 KB for
// occupancy; accumulators live across halves. 1-deep prefetch (R15: 2-deep
// spills). mwr loaded in epilogue only.
#define FMA4X(ACC, WV, BASE)                                                                        \
  ACC[BASE+0] = fmaf(xf.x, WV[0],  fmaf(xf.y, WV[1],  fmaf(xf.z, WV[2],  fmaf(xf.w, WV[3],  ACC[BASE+0])))); \
  ACC[BASE+1] = fmaf(xf.x, WV[4],  fmaf(xf.y, WV[5],  fmaf(xf.z, WV[6],  fmaf(xf.w, WV[7],  ACC[BASE+1])))); \
  ACC[BASE+2] = fmaf(xf.x, WV[8],  fmaf(xf.y, WV[9],  fmaf(xf.z, WV[10], fmaf(xf.w, WV[11], ACC[BASE+2])))); \
  ACC[BASE+3] = fmaf(xf.x, WV[12], fmaf(xf.y, WV[13], fmaf(xf.z, WV[14], fmaf(xf.w, WV[15], ACC[BASE+3]))));

#define INIT_BIAS(ACC, WB)                                                     \
  {                                                                            \
    const f16v* wkb_ = (WB) + 32 * 176;                                        \
    f16v b0 = wkb_[0], b1 = wkb_[1], b2 = wkb_[2], b3 = wkb_[3];               \
    _Pragma("unroll")                                                          \
    for (int c = 0; c < 4; ++c) {                                              \
      ACC[c] = b0[4 * c]; ACC[4 + c] = b1[4 * c];                              \
      ACC[8 + c] = b2[4 * c]; ACC[12 + c] = b3[4 * c];                         \
    }                                                                          \
  }

__global__ __launch_bounds__(256) void k_node(
    const float* __restrict__ x, const float* __restrict__ mw,
    const float* __restrict__ Wq,
    float* __restrict__ beta, float* __restrict__ V) {
  __shared__ float4 xl[64 * 16];       // rotated: [m*16 + ((kc+m)&15)]
  int tid = threadIdx.x;
  int g = blockIdx.x;                  // node group
  int s = blockIdx.y;                  // split 0..4
  int n0 = g * 64;
  int nvalid = NN - n0; if (nvalid > 64) nvalid = 64;
  int m = tid & 63;
  int j = __builtin_amdgcn_readfirstlane(threadIdx.x >> 6);  // wave id 0..3
  int uA = s * 8 + j, uB = uA + 4;

  if (s < 4) {                          // ================= both units beta
    const f16v*   wbA = (const f16v*)Wq + (uA << 2);
    const f16v*   wbB = (const f16v*)Wq + (uB << 2);
    const float4* wpA = (const float4*)Wq + (512 + uA);
    const float4* wpB = (const float4*)Wq + (512 + uB);
    float accA[16], accB[16], accpA, accpB;
    INIT_BIAS(accA, wbA) INIT_BIAS(accB, wbB)
    accpA = wpA[32 * NQCOL].x;
    accpB = wpB[32 * NQCOL].x;

    for (int half = 0; half < 2; ++half) {
      __syncthreads();
      for (int i = tid; i < 64 * 16; i += 256) {
        int mm = i >> 4, kc = i & 15;
        float4 v = make_float4(0.f, 0.f, 0.f, 0.f);
        if (mm < nvalid) v = ((const float4*)(x + (size_t)(n0 + mm) * IC))[half * 16 + kc];
        xl[(mm << 4) + ((kc + mm) & 15)] = v;
      }
      __syncthreads();
      int kb0 = half * 16;
      {
        const f16v*   base  = wbA + kb0 * 176;
        const float4* pbase = wpA + (size_t)kb0 * NQCOL;
        f16v w0 = base[0], w1 = base[1], w2 = base[2], w3 = base[3];
        float4 pw = pbase[0];
        for (int kc = 0; kc < 16; ++kc) {
          f16v nw0, nw1, nw2, nw3; float4 npw;
          if (kc < 15) {
            const f16v* wn = base + (kc + 1) * 176;
            nw0 = wn[0]; nw1 = wn[1]; nw2 = wn[2]; nw3 = wn[3];
            npw = pbase[(size_t)(kc + 1) * NQCOL];
          }
          float4 xf = xl[(m << 4) + ((kc + m) & 15)];
          FMA4X(accA, w0, 0) FMA4X(accA, w1, 4) FMA4X(accA, w2, 8) FMA4X(accA, w3, 12)
          accpA = fmaf(xf.x, pw.x, fmaf(xf.y, pw.y, fmaf(xf.z, pw.z, fmaf(xf.w, pw.w, accpA))));
          if (kc < 15) { w0 = nw0; w1 = nw1; w2 = nw2; w3 = nw3; pw = npw; }
        }
      }
      {
        const f16v*   base  = wbB + kb0 * 176;
        const float4* pbase = wpB + (size_t)kb0 * NQCOL;
        f16v w0 = base[0], w1 = base[1], w2 = base[2], w3 = base[3];
        float4 pw = pbase[0];
        for (int kc = 0; kc < 16; ++kc) {
          f16v nw0, nw1, nw2, nw3; float4 npw;
          if (kc < 15) {
            const f16v* wn = base + (kc + 1) * 176;
            nw0 = wn[0]; nw1 = wn[1]; nw2 = wn[2]; nw3 = wn[3];
            npw = pbase[(size_t)(kc + 1) * NQCOL];
          }
          float4 xf = xl[(m << 4) + ((kc + m) & 15)];
          FMA4X(accB, w0, 0) FMA4X(accB, w1, 4) FMA4X(accB, w2, 8) FMA4X(accB, w3, 12)
          accpB = fmaf(xf.x, pw.x, fmaf(xf.y, pw.y, fmaf(xf.z, pw.z, fmaf(xf.w, pw.w, accpB))));
          if (kc < 15) { w0 = nw0; w1 = nw1; w2 = nw2; w3 = nw3; pw = npw; }
        }
      }
    }
    // epilogue: load mwr now (only used here)
    int mm2 = (m < nvalid) ? m : 0;
    float mwr[16];
    {
      const float4* mp = (const float4*)(mw + (size_t)(n0 + mm2) * 16);
#pragma unroll
      for (int i = 0; i < 4; ++i) {
        float4 t4 = mp[i];
        mwr[4 * i] = t4.x; mwr[4 * i + 1] = t4.y; mwr[4 * i + 2] = t4.z; mwr[4 * i + 3] = t4.w;
      }
    }
    float bsA = accpA, bsB = accpB;
#pragma unroll
    for (int c = 0; c < 16; ++c) {
      bsA = fmaf(accA[c], mwr[c], bsA);
      bsB = fmaf(accB[c], mwr[c], bsB);
    }
    if (m < nvalid) {
      beta[(size_t)(n0 + m) * NSTEP + uA] = bsA * (1.f / 32.f);
      beta[(size_t)(n0 + m) * NSTEP + uB] = bsB * (1.f / 32.f);
    }
  } else {                              // ================= both units V
    const f16v* wbA = (const f16v*)Wq + 136 + ((uA - 32) << 2);
    const f16v* wbB = (const f16v*)Wq + 136 + ((uB - 32) << 2);
    float accA[16], accB[16];
    INIT_BIAS(accA, wbA) INIT_BIAS(accB, wbB)

    for (int half = 0; half < 2; ++half) {
      __syncthreads();
      for (int i = tid; i < 64 * 16; i += 256) {
        int mm = i >> 4, kc = i & 15;
        float4 v = make_float4(0.f, 0.f, 0.f, 0.f);
        if (mm < nvalid) v = ((const float4*)(x + (size_t)(n0 + mm) * IC))[half * 16 + kc];
        xl[(mm << 4) + ((kc + mm) & 15)] = v;
      }
      __syncthreads();
      int kb0 = half * 16;
      {
        const f16v* base = wbA + kb0 * 176;
        f16v w0 = base[0], w1 = base[1], w2 = base[2], w3 = base[3];
        for (int kc = 0; kc < 16; ++kc) {
          f16v nw0, nw1, nw2, nw3;
          if (kc < 15) {
            const f16v* wn = base + (kc + 1) * 176;
            nw0 = wn[0]; nw1 = wn[1]; nw2 = wn[2]; nw3 = wn[3];
          }
          float4 xf = xl[(m << 4) + ((kc + m) & 15)];
          FMA4X(accA, w0, 0) FMA4X(accA, w1, 4) FMA4X(accA, w2, 8) FMA4X(accA, w3, 12)
          if (kc < 15) { w0 = nw0; w1 = nw1; w2 = nw2; w3 = nw3; }
        }
      }
      {
        const f16v* base = wbB + kb0 * 176;
        f16v w0 = base[0], w1 = base[1], w2 = base[2], w3 = base[3];
        for (int kc = 0; kc < 16; ++kc) {
          f16v nw0, nw1, nw2, nw3;
          if (kc < 15) {
            const f16v* wn = base + (kc + 1) * 176;
            nw0 = wn[0]; nw1 = wn[1]; nw2 = wn[2]; nw3 = wn[3];
          }
          float4 xf = xl[(m << 4) + ((kc + m) & 15)];
          FMA4X(accB, w0, 0) FMA4X(accB, w1, 4) FMA4X(accB, w2, 8) FMA4X(accB, w3, 12)
          if (kc < 15) { w0 = nw0; w1 = nw1; w2 = nw2; w3 = nw3; }
        }
      }
    }
    if (m < nvalid) {
      float* voutA = V + (size_t)(n0 + m) * OC + ((uA - 32) << 4);
      float* voutB = V + (size_t)(n0 + m) * OC + ((uB - 32) << 4);
#pragma unroll
      for (int q = 0; q < 4; ++q) {
        float4 o;
        o.x = fmaxf(accA[4 * q], 0.f);     o.y = fmaxf(accA[4 * q + 1], 0.f);
        o.z = fmaxf(accA[4 * q + 2], 0.f); o.w = fmaxf(accA[4 * q + 3], 0.f);
        ((float4*)voutA)[q] = o;
      }
#pragma unroll
      for (int q = 0; q < 4; ++q) {
        float4 o;
        o.x = fmaxf(accB[4 * q], 0.f);     o.y = fmaxf(accB[4 * q + 1], 0.f);
        o.z = fmaxf(accB[4 * q + 2], 0.f); o.w = fmaxf(accB[4 * q + 3], 0.f);
        ((float4*)voutB)[q] = o;
      }
    }
  }
}

// ------- f64 selection scalar: LDS-staged Ud (padded) + x; 16 nodes/block
__global__ __launch_bounds__(256) void k_s64(
    const float* __restrict__ x, const float* __restrict__ mw,
    const double* __restrict__ Ud, const double* __restrict__ ubd,
    double* __restrict__ s64) {
  __shared__ double udl[17 * 130];     // col stride 130 -> bank offset 4/col
  __shared__ float4 xs[16 * 32];
  int tid = threadIdx.x;
  for (int i = tid; i < 17 * IC; i += 256) {
    int cc = i >> 7, kk = i & 127;
    udl[cc * 130 + kk] = Ud[i];
  }
  int n0 = blockIdx.x * 16;
  for (int i = tid; i < 16 * 32; i += 256) {
    int mm = i >> 5, k4 = i & 31;
    int n = n0 + mm;
    xs[i] = (n < NN) ? ((const float4*)(x + (size_t)n * IC))[k4]
                     : make_float4(0.f, 0.f, 0.f, 0.f);
  }
  __syncthreads();
  int m = tid >> 4, c = tid & 15;
  int n = n0 + m;
  const double* uc  = udl + c * 130;
  const double* u16 = udl + 16 * 130;
  double a = 0.0, a16 = 0.0;
  for (int k4 = 0; k4 < 32; ++k4) {
    float4 xv = xs[(m << 5) + k4];
    a = fma((double)xv.x, uc[4 * k4],     a);
    a = fma((double)xv.y, uc[4 * k4 + 1], a);
    a = fma((double)xv.z, uc[4 * k4 + 2], a);
    a = fma((double)xv.w, uc[4 * k4 + 3], a);
  }
#pragma unroll
  for (int q = 0; q < 2; ++q) {        // u16 dot split: lane c -> k4 = 2c, 2c+1
    int k4 = 2 * c + q;
    float4 xv = xs[(m << 5) + k4];
    a16 = fma((double)xv.x, u16[4 * k4],     a16);
    a16 = fma((double)xv.y, u16[4 * k4 + 1], a16);
    a16 = fma((double)xv.z, u16[4 * k4 + 2], a16);
    a16 = fma((double)xv.w, u16[4 * k4 + 3], a16);
  }
  int nm = (n < NN) ? n : 0;
  double part = (a + ubd[c]) * (double)mw[(size_t)nm * 16 + c] + a16;
#pragma unroll
  for (int d = 1; d < 16; d <<= 1) part += __shfl_xor(part, d, 64);
  if (c == 0 && n < NN) s64[n] = (part + ubd[16]) * (1.0 / 1024.0);
}

// -------- keys + byte-0 LDS hist + done-counter pick (256-block grid-stride;
// NOTE: 1000-block one-shot measured ~116-123 us vs <82 at 256 blocks - keep 256)
__global__ void k_keysel(const int* __restrict__ ei, const float* __restrict__ ew,
                         const double* __restrict__ s64,
                         unsigned long long* __restrict__ keys,
                         unsigned* __restrict__ hist, SelState* st) {
  __shared__ unsigned h[256], suf[256];
  __shared__ int last;
  int tid = threadIdx.x;
  h[tid] = 0u;
  if (tid == 0) last = 0;
  __syncthreads();
  for (int e = blockIdx.x * 256 + tid; e < NE; e += gridDim.x * 256) {
    int d = ei[NE + e];
    double v = s64[d] * (double)ew[e];
    unsigned long long u = (unsigned long long)__double_as_longlong(v);
    u = (u & 0x8000000000000000ull) ? ~u : (u | 0x8000000000000000ull);
    keys[e] = u;
    atomicAdd(&h[(unsigned)(u >> 56)], 1u);
  }
  __syncthreads();
  if (h[tid]) atomicAdd(&hist[tid], h[tid]);
  __threadfence();
  __syncthreads();
  if (tid == 0) {
    if (atomicAdd(&st->done[0], 1u) == gridDim.x - 1) last = 1;
  }
  __syncthreads();
  if (!last) return;
  unsigned c = atomicAdd(&hist[tid], 0u);
  suf[tid] = c;
  __syncthreads();
  for (int d = 1; d < 256; d <<= 1) {
    unsigned v = (tid + d < 256) ? suf[tid + d] : 0u;
    __syncthreads();
    suf[tid] += v;
    __syncthreads();
  }
  unsigned r = st->r;
  unsigned exc = suf[tid] - c;
  if (exc < r && exc + c >= r) {
    st->prefix = (unsigned long long)tid;
    st->r = r - exc;
  }
}

// -------- byte-1 pass (LDS hist among byte0-matching keys) -> 16-bit prefix
__global__ void k_radix1(const unsigned long long* __restrict__ keys,
                         unsigned* __restrict__ hist, SelState* st) {
  __shared__ unsigned h[256], suf[256];
  __shared__ int last;
  int tid = threadIdx.x;
  h[tid] = 0u;
  if (tid == 0) last = 0;
  unsigned long long pref = st->prefix;
  __syncthreads();
  unsigned* hp = hist + 256;
  for (int e = blockIdx.x * 256 + tid; e < NE; e += gridDim.x * 256) {
    unsigned long long k = keys[e];
    if ((k >> 56) == pref)
      atomicAdd(&h[(unsigned)((k >> 48) & 255ull)], 1u);
  }
  __syncthreads();
  if (h[tid]) atomicAdd(&hp[tid], h[tid]);
  __threadfence();
  __syncthreads();
  if (tid == 0) {
    if (atomicAdd(&st->done[1], 1u) == gridDim.x - 1) last = 1;
  }
  __syncthreads();
  if (!last) return;
  unsigned c = atomicAdd(&hp[tid], 0u);
  suf[tid] = c;
  __syncthreads();
  for (int d = 1; d < 256; d <<= 1) {
    unsigned v = (tid + d < 256) ? suf[tid + d] : 0u;
    __syncthreads();
    suf[tid] += v;
    __syncthreads();
  }
  unsigned r = st->r;
  unsigned exc = suf[tid] - c;
  if (exc < r && exc + c >= r) {
    st->prefix = (st->prefix << 8) | (unsigned long long)tid;
    st->r = r - exc;
  }
}

// ------- ballot selection bitmask (>P16) + candidate collect; tail resolves
__global__ void k_candsel(const unsigned long long* __restrict__ keys,
                          SelState* st,
                          unsigned long long* __restrict__ flags,
                          unsigned long long* __restrict__ candk, int* __restrict__ cande) {
  __shared__ unsigned h[256], suf[256];
  __shared__ unsigned long long spref;
  __shared__ unsigned sr;
  __shared__ int last;
  int tid = threadIdx.x;
  if (tid == 0) last = 0;
  unsigned P16 = (unsigned)st->prefix;
  for (int e = blockIdx.x * 256 + tid; e < NE; e += gridDim.x * 256) {
    unsigned long long k = keys[e];
    unsigned t16 = (unsigned)(k >> 48);
    unsigned long long bal = __ballot(t16 > P16);
    if ((tid & 63) == 0) flags[e >> 6] = bal;   // lane0's e is 64-aligned
    if (t16 == P16) {
      unsigned pos = atomicAdd(&st->tiec, 1u);
      if (pos < CANDCAP) { candk[pos] = k; cande[pos] = e; }
    }
  }
  __threadfence();
  __syncthreads();
  if (tid == 0) {
    if (atomicAdd(&st->done[2], 1u) == gridDim.x - 1) last = 1;
  }
  __syncthreads();
  if (!last) return;
  // ---- tail: resolve bytes 2..7 among candidates
  unsigned C = atomicAdd(&st->tiec, 0u); if (C > CANDCAP) C = CANDCAP;
  if (tid == 0) { spref = (unsigned long long)P16; sr = st->r; }
  __syncthreads();
  for (int p = 2; p < 8; ++p) {
    h[tid] = 0u;
    __syncthreads();
    int shift = 56 - 8 * p;
    unsigned long long pf = spref;
    unsigned r = sr;
    for (unsigned i = tid; i < C; i += 256) {
      unsigned long long k = candk[i];
      if ((k >> (shift + 8)) == pf) atomicAdd(&h[(unsigned)((k >> shift) & 255ull)], 1u);
    }
    __syncthreads();
    suf[tid] = h[tid];
    __syncthreads();
    for (int d = 1; d < 256; d <<= 1) {
      unsigned v = (tid + d < 256) ? suf[tid + d] : 0u;
      __syncthreads();
      suf[tid] += v;
      __syncthreads();
    }
    unsigned exc = suf[tid] - h[tid];
    if (exc < r && exc + h[tid] >= r) {
      spref = (pf << 8) | (unsigned long long)tid;
      sr = r - exc;
    }
    __syncthreads();
  }
  unsigned long long T = spref;
  unsigned needed = sr;
  // set flag bits for candidates: >T outright; ==T lowest-index ties
  for (unsigned i = tid; i < C; i += 256) {
    unsigned long long k = candk[i];
    int e2 = cande[i];
    bool take = false;
    if (k > T) take = true;
    else if (k == T) {
      unsigned rank = 0;
      for (unsigned q = 0; q < C; ++q)
        rank += (candk[q] == T && cande[q] < e2) ? 1u : 0u;
      take = (rank < needed);
    }
    if (take) atomicOr(&flags[e2 >> 6], 1ull << (e2 & 63));
  }
}

// ------- per-chunk LDS histogram (packed u16, plain global stores)
__global__ __launch_bounds__(256) void k_count1(const int* __restrict__ ei,
                                                const unsigned long long* __restrict__ flags,
                                                unsigned* __restrict__ hpart) {
  __shared__ unsigned hp[HPW];
  int tid = threadIdx.x;
  for (int i = tid; i < HPW; i += 256) hp[i] = 0u;
  __syncthreads();
  int base = blockIdx.x * ECH;
  int lim = base + ECH; if (lim > NE) lim = NE;
  for (int k0 = 0; k0 < RND; k0 += 4) {
    int nn[4]; bool tk[4];
#pragma unroll
    for (int q = 0; q < 4; ++q) {
      int e = base + tid + (k0 + q) * 256;
      bool valid = e < lim;
      unsigned long long w = valid ? flags[e >> 6] : 0ull;
      nn[q] = valid ? ei[e] : 0;
      tk[q] = valid && ((w >> (e & 63)) & 1ull);
    }
#pragma unroll
    for (int q = 0; q < 4; ++q)
      if (tk[q]) atomicAdd(&hp[nn[q] >> 1], 1u << ((nn[q] & 1) * 16));
  }
  __syncthreads();
  unsigned* dst = hpart + (size_t)blockIdx.x * HPW;
  for (int i = tid; i < HPW; i += 256) dst[i] = hp[i];
}

// ------- per-node chunk prefix + cnt + block-sum; tail computes bbase/total
__global__ void k_prefA(const unsigned* __restrict__ hpart,
                        unsigned short* __restrict__ hoffl,
                        unsigned* __restrict__ cnt, unsigned* __restrict__ bsum,
                        unsigned* __restrict__ bbase, unsigned* __restrict__ offar,
                        SelState* st) {
  __shared__ unsigned sd[256];
  __shared__ int last;
  int tid = threadIdx.x;
  if (tid == 0) last = 0;
  int n = blockIdx.x * 256 + tid;
  unsigned tot = 0u;
  if (n < NN) {
    int half = (n & 1) * 16;
    int wi = n >> 1;
#pragma unroll 4
    for (int b = 0; b < CH; ++b) {
      hoffl[(size_t)b * NN + n] = (unsigned short)tot;
      tot += (hpart[(size_t)b * HPW + wi] >> half) & 0xFFFFu;
    }
    cnt[n] = tot;
  }
  sd[tid] = (n < NN) ? tot : 0u;
  __syncthreads();
  for (int s = 128; s > 0; s >>= 1) {
    if (tid < s) sd[tid] += sd[tid + s];
    __syncthreads();
  }
  if (tid == 0) bsum[blockIdx.x] = sd[0];
  __threadfence();
  __syncthreads();
  if (tid == 0) {
    if (atomicAdd(&st->done[3], 1u) == gridDim.x - 1) last = 1;
  }
  __syncthreads();
  if (!last) return;
  unsigned v = (tid < NB) ? bsum[tid] : 0u;
  sd[tid] = v;
  __syncthreads();
  for (int d = 1; d < 256; d <<= 1) {
    unsigned u = (tid >= d) ? sd[tid - d] : 0u;
    __syncthreads();
    sd[tid] += u;
    __syncthreads();
  }
  if (tid < NB) bbase[tid] = sd[tid] - v;
  if (tid == NB - 1) offar[NN] = sd[tid];
}

// ------- offar via intra-block scan
__global__ void k_prefB(const unsigned* __restrict__ cnt, const unsigned* __restrict__ bbase,
                        unsigned* __restrict__ offar) {
  __shared__ unsigned sd[256];
  int tid = threadIdx.x;
  int n = blockIdx.x * 256 + tid;
  unsigned v = (n < NN) ? cnt[n] : 0u;
  sd[tid] = v;
  __syncthreads();
  for (int d = 1; d < 256; d <<= 1) {
    unsigned u = (tid >= d) ? sd[tid - d] : 0u;
    __syncthreads();
    sd[tid] += u;
    __syncthreads();
  }
  if (n < NN) offar[n] = bbase[blockIdx.x] + sd[tid] - v;
}

// ------- per-chunk scatter with LDS relative cursors (no global atomics)
__global__ __launch_bounds__(256) void k_scatterC(const int* __restrict__ ei,
                                                  const unsigned long long* __restrict__ flags,
                                                  const unsigned* __restrict__ offar,
                                                  const unsigned short* __restrict__ hoffl,
                                                  int* __restrict__ csr) {
  __shared__ unsigned rel[HPW];
  int tid = threadIdx.x;
  for (int i = tid; i < HPW; i += 256) rel[i] = 0u;
  __syncthreads();
  int base = blockIdx.x * ECH;
  int lim = base + ECH; if (lim > NE) lim = NE;
  const unsigned short* hl = hoffl + (size_t)blockIdx.x * NN;
  for (int k0 = 0; k0 < RND; k0 += 4) {
    int nn[4]; bool tk[4]; unsigned hb4[4];
#pragma unroll
    for (int q = 0; q < 4; ++q) {
      int e = base + tid + (k0 + q) * 256;
      bool valid = e < lim;
      unsigned long long w = valid ? flags[e >> 6] : 0ull;
      tk[q] = valid && ((w >> (e & 63)) & 1ull);
      nn[q] = valid ? ei[e] : 0;
      hb4[q] = tk[q] ? (offar[nn[q]] + (unsigned)hl[nn[q]]) : 0u;
    }
#pragma unroll
    for (int q = 0; q < 4; ++q) {
      if (tk[q]) {
        int half = (nn[q] & 1) * 16;
        unsigned old = atomicAdd(&rel[nn[q] >> 1], 1u << half);
        unsigned r = (old >> half) & 0xFFFFu;
        unsigned pos = hb4[q] + r;
        if (pos < KSEL) csr[pos] = base + tid + (k0 + q) * 256;
      }
    }
  }
}

// --------- per-node softmax + weighted gather: ONE WAVE PER NODE, no barriers
__global__ __launch_bounds__(256) void k_out(
    const int* __restrict__ ei, const float* __restrict__ ew,
    const float* __restrict__ beta, const float* __restrict__ V,
    const unsigned* __restrict__ offar, const int* __restrict__ csr,
    float* __restrict__ out) {
  int n = (blockIdx.x * 256 + threadIdx.x) >> 6;   // global wave id = node
  int lane = threadIdx.x & 63;
  if (n >= NN) return;
  unsigned beg = offar[n], end = offar[n + 1];
  if (end > (unsigned)KSEL) end = KSEL;
  if (beg > end) beg = end;
  float mval = -INFINITY, den = 0.f;   // softmax state for t = lane&31 (dup'd in hi half)
  float acc0 = 0.f, acc1 = 0.f;        // channels lane, lane+64
  int t0 = lane >> 2, t1 = 16 + (lane >> 2);
  int tl = lane & 31;

  for (unsigned cb = beg; cb < end; cb += 64u) {
    unsigned ce = end - cb; if (ce > 64u) ce = 64u;
    int d_l = 0; float w_l = 0.f;
    if (lane < (int)ce) {
      int e = csr[cb + lane];
      d_l = ei[NE + e];
      w_l = ew[e];
    }
    for (int i = 0; i < (int)ce; ++i) {
      int d = __shfl(d_l, i, 64);
      float wv = __shfl(w_l, i, 64);
      float b = beta[(size_t)d * NSTEP + tl] * wv;
      float mnew = fmaxf(mval, b);
      float sc = expf(mval - mnew);    // 0 when mval was -inf
      float gg = expf(b - mnew);
      den = den * sc + gg;
      mval = mnew;
      float sc0 = __shfl(sc, t0, 64), g0 = __shfl(gg, t0, 64);
      float sc1 = __shfl(sc, t1, 64), g1 = __shfl(gg, t1, 64);
      const float* vr = V + (size_t)d * OC;
      acc0 = acc0 * sc0 + vr[lane] * g0;
      acc1 = acc1 * sc1 + vr[64 + lane] * g1;
    }
  }
  float den0 = __shfl(den, t0, 64);
  float den1 = __shfl(den, t1, 64);
  out[(size_t)n * OC + lane]      = (den0 > 0.f) ? acc0 / den0 : 0.f;
  out[(size_t)n * OC + 64 + lane] = (den1 > 0.f) ? acc1 / den1 : 0.f;
}

// --------------------------------------------------------------------- host
extern "C" void kernel_launch(void* const* d_in, const int* in_sizes, int n_in,
                              void* d_out, int out_size, void* d_ws, size_t ws_size,
                              hipStream_t stream) {
  const float* x     = (const float*)d_in[0];
  const float* p_t   = (const float*)d_in[1];
  const int*   ei    = (const int*)d_in[2];
  const float* ew    = (const float*)d_in[3];
  const float* lin_w = (const float*)d_in[4];
  const float* lin_b = (const float*)d_in[5];
  const float* inc_w = (const float*)d_in[6];
  const float* inc_b = (const float*)d_in[7];
  const float* mw    = (const float*)d_in[8];
  float* out = (float*)d_out;

  char* w = (char*)d_ws;
  size_t off = 0;
  auto alloc = [&](size_t b) -> void* {
    void* p = w + off;
    off += (b + 511) & ~(size_t)511;
    return p;
  };
  float*  Wq    = (float*)alloc((size_t)33 * NQCOL * 4 * 4);
  double* Ud    = (double*)alloc((size_t)17 * IC * 8);
  double* ubd   = (double*)alloc(17 * 8);
  float*  beta  = (float*)alloc((size_t)NN * NSTEP * 4);
  double* s64   = (double*)alloc((size_t)NN * 8);
  float*  V     = (float*)alloc((size_t)NN * OC * 4);
  unsigned long long* keys  = (unsigned long long*)alloc((size_t)NE * 8);
  unsigned long long* flags = (unsigned long long*)alloc((size_t)(NE / 64) * 8);
  unsigned long long* candk = (unsigned long long*)alloc((size_t)CANDCAP * 8);
  int*      cande  = (int*)alloc((size_t)CANDCAP * 4);
  unsigned* hpart  = (unsigned*)alloc((size_t)CH * HPW * 4);
  unsigned short* hoffl = (unsigned short*)alloc((size_t)CH * NN * 2);
  unsigned* cnt    = (unsigned*)alloc((size_t)NN * 4);
  unsigned* offar  = (unsigned*)alloc((size_t)(NN + 1) * 4);
  int*      csr    = (int*)alloc((size_t)KSEL * 4);
  unsigned* hist   = (unsigned*)alloc(512 * 4);
  unsigned* bsum   = (unsigned*)alloc(NB * 4);
  unsigned* bbase  = (unsigned*)alloc(NB * 4);
  SelState* st     = (SelState*)alloc(sizeof(SelState));
  if (off > ws_size) return;

  int init_threads = 33 * NQCOL + 17 * IC + 17 + 512 + 1;
  k_init<<<(init_threads + 255) / 256, 256, 0, stream>>>(p_t, lin_w, lin_b, inc_w, inc_b,
                                                         Wq, Ud, ubd, hist, st);
  k_node<<<dim3((NN + 63) / 64, 5), 256, 0, stream>>>(x, mw, Wq, beta, V);
  k_s64<<<(NN + 15) / 16, 256, 0, stream>>>(x, mw, Ud, ubd, s64);
  k_keysel<<<256, 256, 0, stream>>>(ei, ew, s64, keys, hist, st);
  k_radix1<<<256, 256, 0, stream>>>(keys, hist, st);
  k_candsel<<<256, 256, 0, stream>>>(keys, st, flags, candk, cande);
  k_count1<<<CH, 256, 0, stream>>>(ei, flags, hpart);
  k_prefA<<<NB, 256, 0, stream>>>(hpart, hoffl, cnt, bsum, bbase, offar, st);
  k_prefB<<<NB, 256, 0, stream>>>(cnt, bbase, offar);
  k_scatterC<<<CH, 256, 0, stream>>>(ei, flags, offar, hoffl, csr);
  k_out<<<(NN * 64 + 255) / 256, 256, 0, stream>>>(ei, ew, beta, V, offar, csr, out);
}

// Round 21
// 276.664 us; speedup vs baseline: 1.0903x; 1.0903x over previous
//
#include <hip/hip_runtime.h>

#define NN 20000
#define IC 128
#define OC 128
#define NSTEP 32
#define NE 256000
#define KSEL 128000
#define NB 79        // node-range blocks = ceil(NN/256)
#define CH 64        // edge chunks
#define ECH 4000     // NE / CH
#define RND 16       // ceil(ECH/256)
#define HPW 10000    // packed u16 words per chunk histogram
#define CANDCAP 65536
#define NQCOL 704    // 512 beta + 32 p + 128 V + 32 pad

struct SelState {
  unsigned long long prefix;
  unsigned r;       // remaining rank
  unsigned selc;    // unused
  unsigned tiec;    // candidate count
  unsigned done[8]; // block-done counters
};

typedef __attribute__((ext_vector_type(16))) float f16v;

// ---------------------------------------------------------------- init / fold
__global__ void k_init(const float* __restrict__ p_t, const float* __restrict__ lin_w,
                       const float* __restrict__ lin_b,
                       const float* __restrict__ inc_w, const float* __restrict__ inc_b,
                       float* __restrict__ Wq,
                       double* __restrict__ Ud, double* __restrict__ ubd,
                       unsigned* __restrict__ hist, SelState* st) {
  int i = blockIdx.x * blockDim.x + threadIdx.x;
  if (i < 33 * NQCOL) {
    int k4 = i / NQCOL, col = i - k4 * NQCOL;
    float4 o;
    float* ov = (float*)&o;
    for (int jj = 0; jj < 4; ++jj) {
      int k = 4 * k4 + jj;
      float v = 0.f;
      if (col < 512) {
        int t = col >> 4, c = col & 15;
        if (k < 128) v = inc_w[k * 1024 + t * 32 + c];
        else if (k == 128) v = inc_b[t * 32 + c];
      } else if (col < 544) {
        int t = col - 512;
        if (k < 128) {
          float a = 0.f;
          for (int q = 0; q < 16; ++q) a += inc_w[k * 1024 + t * 32 + 16 + q] * p_t[t * 16 + q];
          v = a;
        } else if (k == 128) {
          float a = 0.f;
          for (int q = 0; q < 16; ++q) a += inc_b[t * 32 + 16 + q] * p_t[t * 16 + q];
          v = a;
        }
      } else if (col < 672) {
        int c = col - 544;
        if (k < 128) v = lin_w[k * OC + c];
        else if (k == 128) v = lin_b[c];
      }
      ov[jj] = v;
    }
    ((float4*)Wq)[i] = o;
    return;
  }
  i -= 33 * NQCOL;
  if (i < 17 * IC) {  // f64 folded selection columns: U (16) and q (1)
    int c = i >> 7, k = i & 127;
    double a = 0.0;
    if (c < 16) {
      for (int t = 0; t < NSTEP; ++t) a += (double)inc_w[k * 1024 + t * 32 + c];
    } else {
      for (int t = 0; t < NSTEP; ++t)
        for (int q = 0; q < 16; ++q)
          a += (double)inc_w[k * 1024 + t * 32 + 16 + q] * (double)p_t[t * 16 + q];
    }
    Ud[c * IC + k] = a;
    return;
  }
  i -= 17 * IC;
  if (i < 17) {
    double a = 0.0;
    if (i < 16) {
      for (int t = 0; t < NSTEP; ++t) a += (double)inc_b[t * 32 + i];
    } else {
      for (int t = 0; t < NSTEP; ++t)
        for (int q = 0; q < 16; ++q)
          a += (double)inc_b[t * 32 + 16 + q] * (double)p_t[t * 16 + q];
    }
    ubd[i] = a;
    return;
  }
  i -= 17;
  if (i < 512) { hist[i] = 0u; return; }
  i -= 512;
  if (i == 0) {
    st->prefix = 0ull; st->r = KSEL; st->selc = 0u; st->tiec = 0u;
    for (int p = 0; p < 8; ++p) st->done[p] = 0u;
  }
}

// ---------------- f32 per-node GEMM: uniform (scalar) weights, 1-deep prefetch
// grid = dim3(313, 5); block = 4 waves; split s covers units s*8..s*8+7
// NOTE (rule bank): 1-deep prefetch is the live-register max (R15: 2-deep ->
// scratch, 5x). f64 must stay OUT of this kernel (R13: regalloc pollution).
// mod-32 rotation on float4 is conflict-free; mod-16 is NOT (R19: 2.1M conflicts).
// LDS is not the occupancy limiter (R19: halving LDS left occupancy at ~32%).
#define FMA4(WV, BASE)                                                                        \
  acc[BASE+0] = fmaf(xf.x, WV[0],  fmaf(xf.y, WV[1],  fmaf(xf.z, WV[2],  fmaf(xf.w, WV[3],  acc[BASE+0])))); \
  acc[BASE+1] = fmaf(xf.x, WV[4],  fmaf(xf.y, WV[5],  fmaf(xf.z, WV[6],  fmaf(xf.w, WV[7],  acc[BASE+1])))); \
  acc[BASE+2] = fmaf(xf.x, WV[8],  fmaf(xf.y, WV[9],  fmaf(xf.z, WV[10], fmaf(xf.w, WV[11], acc[BASE+2])))); \
  acc[BASE+3] = fmaf(xf.x, WV[12], fmaf(xf.y, WV[13], fmaf(xf.z, WV[14], fmaf(xf.w, WV[15], acc[BASE+3]))));

__global__ __launch_bounds__(256) void k_node(
    const float* __restrict__ x, const float* __restrict__ mw,
    const float* __restrict__ Wq,
    float* __restrict__ beta, float* __restrict__ V) {
  __shared__ float4 xl[64 * 32];       // rotated: [m*32 + ((k4+m)&31)]
  int tid = threadIdx.x;
  int g = blockIdx.x;                  // node group
  int s = blockIdx.y;                  // split 0..4
  int n0 = g * 64;
  int nvalid = NN - n0; if (nvalid > 64) nvalid = 64;

  for (int i = tid; i < 64 * 32; i += 256) {
    int mm = i >> 5, k4 = i & 31;
    float4 v = make_float4(0.f, 0.f, 0.f, 0.f);
    if (mm < nvalid) v = ((const float4*)(x + (size_t)(n0 + mm) * IC))[k4];
    xl[(mm << 5) + ((k4 + mm) & 31)] = v;
  }
  int m = tid & 63;
  int j = __builtin_amdgcn_readfirstlane(threadIdx.x >> 6);  // wave id 0..3
  __syncthreads();

  for (int r = 0; r < 2; ++r) {
    int u = s * 8 + j + r * 4;         // uniform unit index
    if (u < 32) {                       // ---- beta unit, timestep t = u
      float mwr[16];
      {
        int mm = (m < nvalid) ? m : 0;
        const float4* mp = (const float4*)(mw + (size_t)(n0 + mm) * 16);
#pragma unroll
        for (int i = 0; i < 4; ++i) {
          float4 t4 = mp[i];
          mwr[4 * i] = t4.x; mwr[4 * i + 1] = t4.y; mwr[4 * i + 2] = t4.z; mwr[4 * i + 3] = t4.w;
        }
      }
      const f16v*   wb = (const f16v*)Wq + (u << 2);      // cols u*16..u*16+15
      const float4* wp = (const float4*)Wq + (512 + u);   // p-col
      float acc[16], accp;
      {
        const f16v* wkb = wb + 32 * 176;
        f16v b0 = wkb[0], b1 = wkb[1], b2 = wkb[2], b3 = wkb[3];
#pragma unroll
        for (int c = 0; c < 4; ++c) {
          acc[c] = b0[4 * c]; acc[4 + c] = b1[4 * c];
          acc[8 + c] = b2[4 * c]; acc[12 + c] = b3[4 * c];
        }
        accp = wp[32 * NQCOL].x;
      }
      f16v w0 = wb[0], w1 = wb[1], w2 = wb[2], w3 = wb[3];
      float4 pw = wp[0];
      for (int k4 = 0; k4 < 32; ++k4) {
        f16v nw0, nw1, nw2, nw3; float4 npw;
        if (k4 < 31) {
          const f16v* wn = wb + (k4 + 1) * 176;
          nw0 = wn[0]; nw1 = wn[1]; nw2 = wn[2]; nw3 = wn[3];
          npw = wp[(k4 + 1) * NQCOL];
        }
        float4 xf = xl[(m << 5) + ((k4 + m) & 31)];
        FMA4(w0, 0) FMA4(w1, 4) FMA4(w2, 8) FMA4(w3, 12)
        accp = fmaf(xf.x, pw.x, fmaf(xf.y, pw.y, fmaf(xf.z, pw.z, fmaf(xf.w, pw.w, accp))));
        if (k4 < 31) { w0 = nw0; w1 = nw1; w2 = nw2; w3 = nw3; pw = npw; }
      }
      float bs = accp;
#pragma unroll
      for (int c = 0; c < 16; ++c) bs = fmaf(acc[c], mwr[c], bs);
      if (m < nvalid) beta[(size_t)(n0 + m) * NSTEP + u] = bs * (1.f / 32.f);
    } else {                            // ---- V unit, cols vc0..vc0+15
      int vg = u - 32;
      int vc0 = vg << 4;
      const f16v* wb = (const f16v*)Wq + 136 + (vg << 2);
      float acc[16];
      {
        const f16v* wkb = wb + 32 * 176;
        f16v b0 = wkb[0], b1 = wkb[1], b2 = wkb[2], b3 = wkb[3];
#pragma unroll
        for (int c = 0; c < 4; ++c) {
          acc[c] = b0[4 * c]; acc[4 + c] = b1[4 * c];
          acc[8 + c] = b2[4 * c]; acc[12 + c] = b3[4 * c];
        }
      }
      f16v w0 = wb[0], w1 = wb[1], w2 = wb[2], w3 = wb[3];
      for (int k4 = 0; k4 < 32; ++k4) {
        f16v nw0, nw1, nw2, nw3;
        if (k4 < 31) {
          const f16v* wn = wb + (k4 + 1) * 176;
          nw0 = wn[0]; nw1 = wn[1]; nw2 = wn[2]; nw3 = wn[3];
        }
        float4 xf = xl[(m << 5) + ((k4 + m) & 31)];
        FMA4(w0, 0) FMA4(w1, 4) FMA4(w2, 8) FMA4(w3, 12)
        if (k4 < 31) { w0 = nw0; w1 = nw1; w2 = nw2; w3 = nw3; }
      }
      if (m < nvalid) {
        float* vout = V + (size_t)(n0 + m) * OC + vc0;
#pragma unroll
        for (int q = 0; q < 4; ++q) {
          float4 o;
          o.x = fmaxf(acc[4 * q], 0.f);     o.y = fmaxf(acc[4 * q + 1], 0.f);
          o.z = fmaxf(acc[4 * q + 2], 0.f); o.w = fmaxf(acc[4 * q + 3], 0.f);
          ((float4*)vout)[q] = o;
        }
      }
    }
  }
}

// ------- f64 selection scalar: LDS-staged Ud (padded) + x; 16 nodes/block
__global__ __launch_bounds__(256) void k_s64(
    const float* __restrict__ x, const float* __restrict__ mw,
    const double* __restrict__ Ud, const double* __restrict__ ubd,
    double* __restrict__ s64) {
  __shared__ double udl[17 * 130];     // col stride 130 -> bank offset 4/col
  __shared__ float4 xs[16 * 32];
  int tid = threadIdx.x;
  for (int i = tid; i < 17 * IC; i += 256) {
    int cc = i >> 7, kk = i & 127;
    udl[cc * 130 + kk] = Ud[i];
  }
  int n0 = blockIdx.x * 16;
  for (int i = tid; i < 16 * 32; i += 256) {
    int mm = i >> 5, k4 = i & 31;
    int n = n0 + mm;
    xs[i] = (n < NN) ? ((const float4*)(x + (size_t)n * IC))[k4]
                     : make_float4(0.f, 0.f, 0.f, 0.f);
  }
  __syncthreads();
  int m = tid >> 4, c = tid & 15;
  int n = n0 + m;
  const double* uc  = udl + c * 130;
  const double* u16 = udl + 16 * 130;
  double a = 0.0, a16 = 0.0;
  for (int k4 = 0; k4 < 32; ++k4) {
    float4 xv = xs[(m << 5) + k4];
    a = fma((double)xv.x, uc[4 * k4],     a);
    a = fma((double)xv.y, uc[4 * k4 + 1], a);
    a = fma((double)xv.z, uc[4 * k4 + 2], a);
    a = fma((double)xv.w, uc[4 * k4 + 3], a);
  }
#pragma unroll
  for (int q = 0; q < 2; ++q) {        // u16 dot split: lane c -> k4 = 2c, 2c+1
    int k4 = 2 * c + q;
    float4 xv = xs[(m << 5) + k4];
    a16 = fma((double)xv.x, u16[4 * k4],     a16);
    a16 = fma((double)xv.y, u16[4 * k4 + 1], a16);
    a16 = fma((double)xv.z, u16[4 * k4 + 2], a16);
    a16 = fma((double)xv.w, u16[4 * k4 + 3], a16);
  }
  int nm = (n < NN) ? n : 0;
  double part = (a + ubd[c]) * (double)mw[(size_t)nm * 16 + c] + a16;
#pragma unroll
  for (int d = 1; d < 16; d <<= 1) part += __shfl_xor(part, d, 64);
  if (c == 0 && n < NN) s64[n] = (part + ubd[16]) * (1.0 / 1024.0);
}

// -------- keys + byte-0 LDS hist + done-counter pick (256-block grid-stride;
// NOTE: 1000-block one-shot measured ~116-123 us vs <82 at 256 blocks - keep 256)
__global__ void k_keysel(const int* __restrict__ ei, const float* __restrict__ ew,
                         const double* __restrict__ s64,
                         unsigned long long* __restrict__ keys,
                         unsigned* __restrict__ hist, SelState* st) {
  __shared__ unsigned h[256], suf[256];
  __shared__ int last;
  int tid = threadIdx.x;
  h[tid] = 0u;
  if (tid == 0) last = 0;
  __syncthreads();
  for (int e = blockIdx.x * 256 + tid; e < NE; e += gridDim.x * 256) {
    int d = ei[NE + e];
    double v = s64[d] * (double)ew[e];
    unsigned long long u = (unsigned long long)__double_as_longlong(v);
    u = (u & 0x8000000000000000ull) ? ~u : (u | 0x8000000000000000ull);
    keys[e] = u;
    atomicAdd(&h[(unsigned)(u >> 56)], 1u);
  }
  __syncthreads();
  if (h[tid]) atomicAdd(&hist[tid], h[tid]);
  __threadfence();
  __syncthreads();
  if (tid == 0) {
    if (atomicAdd(&st->done[0], 1u) == gridDim.x - 1) last = 1;
  }
  __syncthreads();
  if (!last) return;
  unsigned c = atomicAdd(&hist[tid], 0u);
  suf[tid] = c;
  __syncthreads();
  for (int d = 1; d < 256; d <<= 1) {
    unsigned v = (tid + d < 256) ? suf[tid + d] : 0u;
    __syncthreads();
    suf[tid] += v;
    __syncthreads();
  }
  unsigned r = st->r;
  unsigned exc = suf[tid] - c;
  if (exc < r && exc + c >= r) {
    st->prefix = (unsigned long long)tid;
    st->r = r - exc;
  }
}

// -------- byte-1 pass (LDS hist among byte0-matching keys) -> 16-bit prefix
__global__ void k_radix1(const unsigned long long* __restrict__ keys,
                         unsigned* __restrict__ hist, SelState* st) {
  __shared__ unsigned h[256], suf[256];
  __shared__ int last;
  int tid = threadIdx.x;
  h[tid] = 0u;
  if (tid == 0) last = 0;
  unsigned long long pref = st->prefix;
  __syncthreads();
  unsigned* hp = hist + 256;
  for (int e = blockIdx.x * 256 + tid; e < NE; e += gridDim.x * 256) {
    unsigned long long k = keys[e];
    if ((k >> 56) == pref)
      atomicAdd(&h[(unsigned)((k >> 48) & 255ull)], 1u);
  }
  __syncthreads();
  if (h[tid]) atomicAdd(&hp[tid], h[tid]);
  __threadfence();
  __syncthreads();
  if (tid == 0) {
    if (atomicAdd(&st->done[1], 1u) == gridDim.x - 1) last = 1;
  }
  __syncthreads();
  if (!last) return;
  unsigned c = atomicAdd(&hp[tid], 0u);
  suf[tid] = c;
  __syncthreads();
  for (int d = 1; d < 256; d <<= 1) {
    unsigned v = (tid + d < 256) ? suf[tid + d] : 0u;
    __syncthreads();
    suf[tid] += v;
    __syncthreads();
  }
  unsigned r = st->r;
  unsigned exc = suf[tid] - c;
  if (exc < r && exc + c >= r) {
    st->prefix = (st->prefix << 8) | (unsigned long long)tid;
    st->r = r - exc;
  }
}

// ------- ballot selection bitmask (>P16) + candidate collect; tail resolves
__global__ void k_candsel(const unsigned long long* __restrict__ keys,
                          SelState* st,
                          unsigned long long* __restrict__ flags,
                          unsigned long long* __restrict__ candk, int* __restrict__ cande) {
  __shared__ unsigned h[256], suf[256];
  __shared__ unsigned long long spref;
  __shared__ unsigned sr;
  __shared__ int last;
  int tid = threadIdx.x;
  if (tid == 0) last = 0;
  unsigned P16 = (unsigned)st->prefix;
  for (int e = blockIdx.x * 256 + tid; e < NE; e += gridDim.x * 256) {
    unsigned long long k = keys[e];
    unsigned t16 = (unsigned)(k >> 48);
    unsigned long long bal = __ballot(t16 > P16);
    if ((tid & 63) == 0) flags[e >> 6] = bal;   // lane0's e is 64-aligned
    if (t16 == P16) {
      unsigned pos = atomicAdd(&st->tiec, 1u);
      if (pos < CANDCAP) { candk[pos] = k; cande[pos] = e; }
    }
  }
  __threadfence();
  __syncthreads();
  if (tid == 0) {
    if (atomicAdd(&st->done[2], 1u) == gridDim.x - 1) last = 1;
  }
  __syncthreads();
  if (!last) return;
  // ---- tail: resolve bytes 2..7 among candidates
  unsigned C = atomicAdd(&st->tiec, 0u); if (C > CANDCAP) C = CANDCAP;
  if (tid == 0) { spref = (unsigned long long)P16; sr = st->r; }
  __syncthreads();
  for (int p = 2; p < 8; ++p) {
    h[tid] = 0u;
    __syncthreads();
    int shift = 56 - 8 * p;
    unsigned long long pf = spref;
    unsigned r = sr;
    for (unsigned i = tid; i < C; i += 256) {
      unsigned long long k = candk[i];
      if ((k >> (shift + 8)) == pf) atomicAdd(&h[(unsigned)((k >> shift) & 255ull)], 1u);
    }
    __syncthreads();
    suf[tid] = h[tid];
    __syncthreads();
    for (int d = 1; d < 256; d <<= 1) {
      unsigned v = (tid + d < 256) ? suf[tid + d] : 0u;
      __syncthreads();
      suf[tid] += v;
      __syncthreads();
    }
    unsigned exc = suf[tid] - h[tid];
    if (exc < r && exc + h[tid] >= r) {
      spref = (pf << 8) | (unsigned long long)tid;
      sr = r - exc;
    }
    __syncthreads();
  }
  unsigned long long T = spref;
  unsigned needed = sr;
  // set flag bits for candidates: >T outright; ==T lowest-index ties
  for (unsigned i = tid; i < C; i += 256) {
    unsigned long long k = candk[i];
    int e2 = cande[i];
    bool take = false;
    if (k > T) take = true;
    else if (k == T) {
      unsigned rank = 0;
      for (unsigned q = 0; q < C; ++q)
        rank += (candk[q] == T && cande[q] < e2) ? 1u : 0u;
      take = (rank < needed);
    }
    if (take) atomicOr(&flags[e2 >> 6], 1ull << (e2 & 63));
  }
}

// ------- per-chunk LDS histogram (packed u16, plain global stores)
__global__ __launch_bounds__(256) void k_count1(const int* __restrict__ ei,
                                                const unsigned long long* __restrict__ flags,
                                                unsigned* __restrict__ hpart) {
  __shared__ unsigned hp[HPW];
  int tid = threadIdx.x;
  for (int i = tid; i < HPW; i += 256) hp[i] = 0u;
  __syncthreads();
  int base = blockIdx.x * ECH;
  int lim = base + ECH; if (lim > NE) lim = NE;
  for (int k0 = 0; k0 < RND; k0 += 4) {
    int nn[4]; bool tk[4];
#pragma unroll
    for (int q = 0; q < 4; ++q) {
      int e = base + tid + (k0 + q) * 256;
      bool valid = e < lim;
      unsigned long long w = valid ? flags[e >> 6] : 0ull;
      nn[q] = valid ? ei[e] : 0;
      tk[q] = valid && ((w >> (e & 63)) & 1ull);
    }
#pragma unroll
    for (int q = 0; q < 4; ++q)
      if (tk[q]) atomicAdd(&hp[nn[q] >> 1], 1u << ((nn[q] & 1) * 16));
  }
  __syncthreads();
  unsigned* dst = hpart + (size_t)blockIdx.x * HPW;
  for (int i = tid; i < HPW; i += 256) dst[i] = hp[i];
}

// ------- per-node chunk prefix + cnt + block-sum; tail computes bbase/total
__global__ void k_prefA(const unsigned* __restrict__ hpart,
                        unsigned short* __restrict__ hoffl,
                        unsigned* __restrict__ cnt, unsigned* __restrict__ bsum,
                        unsigned* __restrict__ bbase, unsigned* __restrict__ offar,
                        SelState* st) {
  __shared__ unsigned sd[256];
  __shared__ int last;
  int tid = threadIdx.x;
  if (tid == 0) last = 0;
  int n = blockIdx.x * 256 + tid;
  unsigned tot = 0u;
  if (n < NN) {
    int half = (n & 1) * 16;
    int wi = n >> 1;
#pragma unroll 4
    for (int b = 0; b < CH; ++b) {
      hoffl[(size_t)b * NN + n] = (unsigned short)tot;
      tot += (hpart[(size_t)b * HPW + wi] >> half) & 0xFFFFu;
    }
    cnt[n] = tot;
  }
  sd[tid] = (n < NN) ? tot : 0u;
  __syncthreads();
  for (int s = 128; s > 0; s >>= 1) {
    if (tid < s) sd[tid] += sd[tid + s];
    __syncthreads();
  }
  if (tid == 0) bsum[blockIdx.x] = sd[0];
  __threadfence();
  __syncthreads();
  if (tid == 0) {
    if (atomicAdd(&st->done[3], 1u) == gridDim.x - 1) last = 1;
  }
  __syncthreads();
  if (!last) return;
  unsigned v = (tid < NB) ? bsum[tid] : 0u;
  sd[tid] = v;
  __syncthreads();
  for (int d = 1; d < 256; d <<= 1) {
    unsigned u = (tid >= d) ? sd[tid - d] : 0u;
    __syncthreads();
    sd[tid] += u;
    __syncthreads();
  }
  if (tid < NB) bbase[tid] = sd[tid] - v;
  if (tid == NB - 1) offar[NN] = sd[tid];
}

// ------- offar via intra-block scan
__global__ void k_prefB(const unsigned* __restrict__ cnt, const unsigned* __restrict__ bbase,
                        unsigned* __restrict__ offar) {
  __shared__ unsigned sd[256];
  int tid = threadIdx.x;
  int n = blockIdx.x * 256 + tid;
  unsigned v = (n < NN) ? cnt[n] : 0u;
  sd[tid] = v;
  __syncthreads();
  for (int d = 1; d < 256; d <<= 1) {
    unsigned u = (tid >= d) ? sd[tid - d] : 0u;
    __syncthreads();
    sd[tid] += u;
    __syncthreads();
  }
  if (n < NN) offar[n] = bbase[blockIdx.x] + sd[tid] - v;
}

// ------- per-chunk scatter with LDS relative cursors (no global atomics)
__global__ __launch_bounds__(256) void k_scatterC(const int* __restrict__ ei,
                                                  const unsigned long long* __restrict__ flags,
                                                  const unsigned* __restrict__ offar,
                                                  const unsigned short* __restrict__ hoffl,
                                                  int* __restrict__ csr) {
  __shared__ unsigned rel[HPW];
  int tid = threadIdx.x;
  for (int i = tid; i < HPW; i += 256) rel[i] = 0u;
  __syncthreads();
  int base = blockIdx.x * ECH;
  int lim = base + ECH; if (lim > NE) lim = NE;
  const unsigned short* hl = hoffl + (size_t)blockIdx.x * NN;
  for (int k0 = 0; k0 < RND; k0 += 4) {
    int nn[4]; bool tk[4]; unsigned hb4[4];
#pragma unroll
    for (int q = 0; q < 4; ++q) {
      int e = base + tid + (k0 + q) * 256;
      bool valid = e < lim;
      unsigned long long w = valid ? flags[e >> 6] : 0ull;
      tk[q] = valid && ((w >> (e & 63)) & 1ull);
      nn[q] = valid ? ei[e] : 0;
      hb4[q] = tk[q] ? (offar[nn[q]] + (unsigned)hl[nn[q]]) : 0u;
    }
#pragma unroll
    for (int q = 0; q < 4; ++q) {
      if (tk[q]) {
        int half = (nn[q] & 1) * 16;
        unsigned old = atomicAdd(&rel[nn[q] >> 1], 1u << half);
        unsigned r = (old >> half) & 0xFFFFu;
        unsigned pos = hb4[q] + r;
        if (pos < KSEL) csr[pos] = base + tid + (k0 + q) * 256;
      }
    }
  }
}

// --------- per-node softmax + weighted gather: ONE WAVE PER NODE, no barriers
__global__ __launch_bounds__(256) void k_out(
    const int* __restrict__ ei, const float* __restrict__ ew,
    const float* __restrict__ beta, const float* __restrict__ V,
    const unsigned* __restrict__ offar, const int* __restrict__ csr,
    float* __restrict__ out) {
  int n = (blockIdx.x * 256 + threadIdx.x) >> 6;   // global wave id = node
  int lane = threadIdx.x & 63;
  if (n >= NN) return;
  unsigned beg = offar[n], end = offar[n + 1];
  if (end > (unsigned)KSEL) end = KSEL;
  if (beg > end) beg = end;
  float mval = -INFINITY, den = 0.f;   // softmax state for t = lane&31 (dup'd in hi half)
  float acc0 = 0.f, acc1 = 0.f;        // channels lane, lane+64
  int t0 = lane >> 2, t1 = 16 + (lane >> 2);
  int tl = lane & 31;

  for (unsigned cb = beg; cb < end; cb += 64u) {
    unsigned ce = end - cb; if (ce > 64u) ce = 64u;
    int d_l = 0; float w_l = 0.f;
    if (lane < (int)ce) {
      int e = csr[cb + lane];
      d_l = ei[NE + e];
      w_l = ew[e];
    }
    for (int i = 0; i < (int)ce; ++i) {
      int d = __shfl(d_l, i, 64);
      float wv = __shfl(w_l, i, 64);
      float b = beta[(size_t)d * NSTEP + tl] * wv;
      float mnew = fmaxf(mval, b);
      float sc = expf(mval - mnew);    // 0 when mval was -inf
      float gg = expf(b - mnew);
      den = den * sc + gg;
      mval = mnew;
      float sc0 = __shfl(sc, t0, 64), g0 = __shfl(gg, t0, 64);
      float sc1 = __shfl(sc, t1, 64), g1 = __shfl(gg, t1, 64);
      const float* vr = V + (size_t)d * OC;
      acc0 = acc0 * sc0 + vr[lane] * g0;
      acc1 = acc1 * sc1 + vr[64 + lane] * g1;
    }
  }
  float den0 = __shfl(den, t0, 64);
  float den1 = __shfl(den, t1, 64);
  out[(size_t)n * OC + lane]      = (den0 > 0.f) ? acc0 / den0 : 0.f;
  out[(size_t)n * OC + 64 + lane] = (den1 > 0.f) ? acc1 / den1 : 0.f;
}

// --------------------------------------------------------------------- host
extern "C" void kernel_launch(void* const* d_in, const int* in_sizes, int n_in,
                              void* d_out, int out_size, void* d_ws, size_t ws_size,
                              hipStream_t stream) {
  const float* x     = (const float*)d_in[0];
  const float* p_t   = (const float*)d_in[1];
  const int*   ei    = (const int*)d_in[2];
  const float* ew    = (const float*)d_in[3];
  const float* lin_w = (const float*)d_in[4];
  const float* lin_b = (const float*)d_in[5];
  const float* inc_w = (const float*)d_in[6];
  const float* inc_b = (const float*)d_in[7];
  const float* mw    = (const float*)d_in[8];
  float* out = (float*)d_out;

  char* w = (char*)d_ws;
  size_t off = 0;
  auto alloc = [&](size_t b) -> void* {
    void* p = w + off;
    off += (b + 511) & ~(size_t)511;
    return p;
  };
  float*  Wq    = (float*)alloc((size_t)33 * NQCOL * 4 * 4);
  double* Ud    = (double*)alloc((size_t)17 * IC * 8);
  double* ubd   = (double*)alloc(17 * 8);
  float*  beta  = (float*)alloc((size_t)NN * NSTEP * 4);
  double* s64   = (double*)alloc((size_t)NN * 8);
  float*  V     = (float*)alloc((size_t)NN * OC * 4);
  unsigned long long* keys  = (unsigned long long*)alloc((size_t)NE * 8);
  unsigned long long* flags = (unsigned long long*)alloc((size_t)(NE / 64) * 8);
  unsigned long long* candk = (unsigned long long*)alloc((size_t)CANDCAP * 8);
  int*      cande  = (int*)alloc((size_t)CANDCAP * 4);
  unsigned* hpart  = (unsigned*)alloc((size_t)CH * HPW * 4);
  unsigned short* hoffl = (unsigned short*)alloc((size_t)CH * NN * 2);
  unsigned* cnt    = (unsigned*)alloc((size_t)NN * 4);
  unsigned* offar  = (unsigned*)alloc((size_t)(NN + 1) * 4);
  int*      csr    = (int*)alloc((size_t)KSEL * 4);
  unsigned* hist   = (unsigned*)alloc(512 * 4);
  unsigned* bsum   = (unsigned*)alloc(NB * 4);
  unsigned* bbase  = (unsigned*)alloc(NB * 4);
  SelState* st     = (SelState*)alloc(sizeof(SelState));
  if (off > ws_size) return;

  int init_threads = 33 * NQCOL + 17 * IC + 17 + 512 + 1;
  k_init<<<(init_threads + 255) / 256, 256, 0, stream>>>(p_t, lin_w, lin_b, inc_w, inc_b,
                                                         Wq, Ud, ubd, hist, st);
  k_node<<<dim3((NN + 63) / 64, 5), 256, 0, stream>>>(x, mw, Wq, beta, V);
  k_s64<<<(NN + 15) / 16, 256, 0, stream>>>(x, mw, Ud, ubd, s64);
  k_keysel<<<256, 256, 0, stream>>>(ei, ew, s64, keys, hist, st);
  k_radix1<<<256, 256, 0, stream>>>(keys, hist, st);
  k_candsel<<<256, 256, 0, stream>>>(keys, st, flags, candk, cande);
  k_count1<<<CH, 256, 0, stream>>>(ei, flags, hpart);
  k_prefA<<<NB, 256, 0, stream>>>(hpart, hoffl, cnt, bsum, bbase, offar, st);
  k_prefB<<<NB, 256, 0, stream>>>(cnt, bbase, offar);
  k_scatterC<<<CH, 256, 0, stream>>>(ei, flags, offar, hoffl, csr);
  k_out<<<(NN * 64 + 255) / 256, 256, 0, stream>>>(ei, ew, beta, V, offar, csr, out);
}

// Round 22
// 276.220 us; speedup vs baseline: 1.0921x; 1.0016x over previous
//
#include <hip/hip_runtime.h>

#define NN 20000
#define IC 128
#define OC 128
#define NSTEP 32
#define NE 256000
#define KSEL 128000
#define NB 79        // node-range blocks = ceil(NN/256)
#define CH 64        // edge chunks
#define ECH 4000     // NE / CH
#define RND 16       // ceil(ECH/256)
#define HPW 10000    // packed u16 words per chunk histogram
#define CANDCAP 65536
#define NQCOL 704    // 512 beta + 32 p + 128 V + 32 pad
#define NGRP 313     // node groups = ceil(NN/64)

struct SelState {
  unsigned long long prefix;
  unsigned r;       // remaining rank
  unsigned selc;    // unused
  unsigned tiec;    // candidate count
  unsigned done[8]; // block-done counters
};

typedef __attribute__((ext_vector_type(16))) float f16v;

// ---------------------------------------------------------------- init / fold
__global__ void k_init(const float* __restrict__ p_t, const float* __restrict__ lin_w,
                       const float* __restrict__ lin_b,
                       const float* __restrict__ inc_w, const float* __restrict__ inc_b,
                       float* __restrict__ Wq,
                       double* __restrict__ Ud, double* __restrict__ ubd,
                       unsigned* __restrict__ hist, SelState* st) {
  int i = blockIdx.x * blockDim.x + threadIdx.x;
  if (i < 33 * NQCOL) {
    int k4 = i / NQCOL, col = i - k4 * NQCOL;
    float4 o;
    float* ov = (float*)&o;
    for (int jj = 0; jj < 4; ++jj) {
      int k = 4 * k4 + jj;
      float v = 0.f;
      if (col < 512) {
        int t = col >> 4, c = col & 15;
        if (k < 128) v = inc_w[k * 1024 + t * 32 + c];
        else if (k == 128) v = inc_b[t * 32 + c];
      } else if (col < 544) {
        int t = col - 512;
        if (k < 128) {
          float a = 0.f;
          for (int q = 0; q < 16; ++q) a += inc_w[k * 1024 + t * 32 + 16 + q] * p_t[t * 16 + q];
          v = a;
        } else if (k == 128) {
          float a = 0.f;
          for (int q = 0; q < 16; ++q) a += inc_b[t * 32 + 16 + q] * p_t[t * 16 + q];
          v = a;
        }
      } else if (col < 672) {
        int c = col - 544;
        if (k < 128) v = lin_w[k * OC + c];
        else if (k == 128) v = lin_b[c];
      }
      ov[jj] = v;
    }
    ((float4*)Wq)[i] = o;
    return;
  }
  i -= 33 * NQCOL;
  if (i < 17 * IC) {  // f64 folded selection columns: U (16) and q (1)
    int c = i >> 7, k = i & 127;
    double a = 0.0;
    if (c < 16) {
      for (int t = 0; t < NSTEP; ++t) a += (double)inc_w[k * 1024 + t * 32 + c];
    } else {
      for (int t = 0; t < NSTEP; ++t)
        for (int q = 0; q < 16; ++q)
          a += (double)inc_w[k * 1024 + t * 32 + 16 + q] * (double)p_t[t * 16 + q];
    }
    Ud[c * IC + k] = a;
    return;
  }
  i -= 17 * IC;
  if (i < 17) {
    double a = 0.0;
    if (i < 16) {
      for (int t = 0; t < NSTEP; ++t) a += (double)inc_b[t * 32 + i];
    } else {
      for (int t = 0; t < NSTEP; ++t)
        for (int q = 0; q < 16; ++q)
          a += (double)inc_b[t * 32 + 16 + q] * (double)p_t[t * 16 + q];
    }
    ubd[i] = a;
    return;
  }
  i -= 17;
  if (i < 512) { hist[i] = 0u; return; }
  i -= 512;
  if (i == 0) {
    st->prefix = 0ull; st->r = KSEL; st->selc = 0u; st->tiec = 0u;
    for (int p = 0; p < 8; ++p) st->done[p] = 0u;
  }
}

// ---------------- f32 per-node GEMM: uniform (scalar) weights, 1-deep prefetch
// grid = 1600 blocks 1D, XCD-aware: bid = chunk*40 + s*8 + glocal,
// g = chunk*8 + glocal. 40 % 8 == 0 so all 5 splits of a group share
// bid%8 (same XCD under round-robin) and sit in one 40-block dispatch
// window -> x-tile fetched once per XCD L2, reused 5x.
// NOTE (rule bank): 1-deep prefetch is the live-register max (R15: 2-deep ->
// scratch, 5x). f64 must stay OUT of this kernel (R13: regalloc pollution).
// mod-32 rotation on float4 is conflict-free; mod-16 is NOT (R19: 2.1M conflicts).
// LDS is not the occupancy limiter (R19: halving LDS left occupancy at ~32%).
#define FMA4(WV, BASE)                                                                        \
  acc[BASE+0] = fmaf(xf.x, WV[0],  fmaf(xf.y, WV[1],  fmaf(xf.z, WV[2],  fmaf(xf.w, WV[3],  acc[BASE+0])))); \
  acc[BASE+1] = fmaf(xf.x, WV[4],  fmaf(xf.y, WV[5],  fmaf(xf.z, WV[6],  fmaf(xf.w, WV[7],  acc[BASE+1])))); \
  acc[BASE+2] = fmaf(xf.x, WV[8],  fmaf(xf.y, WV[9],  fmaf(xf.z, WV[10], fmaf(xf.w, WV[11], acc[BASE+2])))); \
  acc[BASE+3] = fmaf(xf.x, WV[12], fmaf(xf.y, WV[13], fmaf(xf.z, WV[14], fmaf(xf.w, WV[15], acc[BASE+3]))));

__global__ __launch_bounds__(256) void k_node(
    const float* __restrict__ x, const float* __restrict__ mw,
    const float* __restrict__ Wq,
    float* __restrict__ beta, float* __restrict__ V) {
  __shared__ float4 xl[64 * 32];       // rotated: [m*32 + ((k4+m)&31)]
  int tid = threadIdx.x;
  int bid = blockIdx.x;
  int chunk = bid / 40;
  int within = bid - chunk * 40;
  int s = within >> 3;                 // split 0..4
  int g = chunk * 8 + (within & 7);    // node group
  if (g >= NGRP) return;               // padded group (uniform per block)
  int n0 = g * 64;
  int nvalid = NN - n0; if (nvalid > 64) nvalid = 64;

  for (int i = tid; i < 64 * 32; i += 256) {
    int mm = i >> 5, k4 = i & 31;
    float4 v = make_float4(0.f, 0.f, 0.f, 0.f);
    if (mm < nvalid) v = ((const float4*)(x + (size_t)(n0 + mm) * IC))[k4];
    xl[(mm << 5) + ((k4 + mm) & 31)] = v;
  }
  int m = tid & 63;
  int j = __builtin_amdgcn_readfirstlane(threadIdx.x >> 6);  // wave id 0..3
  __syncthreads();

  for (int r = 0; r < 2; ++r) {
    int u = s * 8 + j + r * 4;         // uniform unit index
    if (u < 32) {                       // ---- beta unit, timestep t = u
      float mwr[16];
      {
        int mm = (m < nvalid) ? m : 0;
        const float4* mp = (const float4*)(mw + (size_t)(n0 + mm) * 16);
#pragma unroll
        for (int i = 0; i < 4; ++i) {
          float4 t4 = mp[i];
          mwr[4 * i] = t4.x; mwr[4 * i + 1] = t4.y; mwr[4 * i + 2] = t4.z; mwr[4 * i + 3] = t4.w;
        }
      }
      const f16v*   wb = (const f16v*)Wq + (u << 2);      // cols u*16..u*16+15
      const float4* wp = (const float4*)Wq + (512 + u);   // p-col
      float acc[16], accp;
      {
        const f16v* wkb = wb + 32 * 176;
        f16v b0 = wkb[0], b1 = wkb[1], b2 = wkb[2], b3 = wkb[3];
#pragma unroll
        for (int c = 0; c < 4; ++c) {
          acc[c] = b0[4 * c]; acc[4 + c] = b1[4 * c];
          acc[8 + c] = b2[4 * c]; acc[12 + c] = b3[4 * c];
        }
        accp = wp[32 * NQCOL].x;
      }
      f16v w0 = wb[0], w1 = wb[1], w2 = wb[2], w3 = wb[3];
      float4 pw = wp[0];
      for (int k4 = 0; k4 < 32; ++k4) {
        f16v nw0, nw1, nw2, nw3; float4 npw;
        if (k4 < 31) {
          const f16v* wn = wb + (k4 + 1) * 176;
          nw0 = wn[0]; nw1 = wn[1]; nw2 = wn[2]; nw3 = wn[3];
          npw = wp[(k4 + 1) * NQCOL];
        }
        float4 xf = xl[(m << 5) + ((k4 + m) & 31)];
        FMA4(w0, 0) FMA4(w1, 4) FMA4(w2, 8) FMA4(w3, 12)
        accp = fmaf(xf.x, pw.x, fmaf(xf.y, pw.y, fmaf(xf.z, pw.z, fmaf(xf.w, pw.w, accp))));
        if (k4 < 31) { w0 = nw0; w1 = nw1; w2 = nw2; w3 = nw3; pw = npw; }
      }
      float bs = accp;
#pragma unroll
      for (int c = 0; c < 16; ++c) bs = fmaf(acc[c], mwr[c], bs);
      if (m < nvalid) beta[(size_t)(n0 + m) * NSTEP + u] = bs * (1.f / 32.f);
    } else {                            // ---- V unit, cols vc0..vc0+15
      int vg = u - 32;
      int vc0 = vg << 4;
      const f16v* wb = (const f16v*)Wq + 136 + (vg << 2);
      float acc[16];
      {
        const f16v* wkb = wb + 32 * 176;
        f16v b0 = wkb[0], b1 = wkb[1], b2 = wkb[2], b3 = wkb[3];
#pragma unroll
        for (int c = 0; c < 4; ++c) {
          acc[c] = b0[4 * c]; acc[4 + c] = b1[4 * c];
          acc[8 + c] = b2[4 * c]; acc[12 + c] = b3[4 * c];
        }
      }
      f16v w0 = wb[0], w1 = wb[1], w2 = wb[2], w3 = wb[3];
      for (int k4 = 0; k4 < 32; ++k4) {
        f16v nw0, nw1, nw2, nw3;
        if (k4 < 31) {
          const f16v* wn = wb + (k4 + 1) * 176;
          nw0 = wn[0]; nw1 = wn[1]; nw2 = wn[2]; nw3 = wn[3];
        }
        float4 xf = xl[(m << 5) + ((k4 + m) & 31)];
        FMA4(w0, 0) FMA4(w1, 4) FMA4(w2, 8) FMA4(w3, 12)
        if (k4 < 31) { w0 = nw0; w1 = nw1; w2 = nw2; w3 = nw3; }
      }
      if (m < nvalid) {
        float* vout = V + (size_t)(n0 + m) * OC + vc0;
#pragma unroll
        for (int q = 0; q < 4; ++q) {
          float4 o;
          o.x = fmaxf(acc[4 * q], 0.f);     o.y = fmaxf(acc[4 * q + 1], 0.f);
          o.z = fmaxf(acc[4 * q + 2], 0.f); o.w = fmaxf(acc[4 * q + 3], 0.f);
          ((float4*)vout)[q] = o;
        }
      }
    }
  }
}

// ------- f64 selection scalar: LDS-staged Ud (padded) + x; 16 nodes/block
__global__ __launch_bounds__(256) void k_s64(
    const float* __restrict__ x, const float* __restrict__ mw,
    const double* __restrict__ Ud, const double* __restrict__ ubd,
    double* __restrict__ s64) {
  __shared__ double udl[17 * 130];     // col stride 130 -> bank offset 4/col
  __shared__ float4 xs[16 * 32];
  int tid = threadIdx.x;
  for (int i = tid; i < 17 * IC; i += 256) {
    int cc = i >> 7, kk = i & 127;
    udl[cc * 130 + kk] = Ud[i];
  }
  int n0 = blockIdx.x * 16;
  for (int i = tid; i < 16 * 32; i += 256) {
    int mm = i >> 5, k4 = i & 31;
    int n = n0 + mm;
    xs[i] = (n < NN) ? ((const float4*)(x + (size_t)n * IC))[k4]
                     : make_float4(0.f, 0.f, 0.f, 0.f);
  }
  __syncthreads();
  int m = tid >> 4, c = tid & 15;
  int n = n0 + m;
  const double* uc  = udl + c * 130;
  const double* u16 = udl + 16 * 130;
  double a = 0.0, a16 = 0.0;
  for (int k4 = 0; k4 < 32; ++k4) {
    float4 xv = xs[(m << 5) + k4];
    a = fma((double)xv.x, uc[4 * k4],     a);
    a = fma((double)xv.y, uc[4 * k4 + 1], a);
    a = fma((double)xv.z, uc[4 * k4 + 2], a);
    a = fma((double)xv.w, uc[4 * k4 + 3], a);
  }
#pragma unroll
  for (int q = 0; q < 2; ++q) {        // u16 dot split: lane c -> k4 = 2c, 2c+1
    int k4 = 2 * c + q;
    float4 xv = xs[(m << 5) + k4];
    a16 = fma((double)xv.x, u16[4 * k4],     a16);
    a16 = fma((double)xv.y, u16[4 * k4 + 1], a16);
    a16 = fma((double)xv.z, u16[4 * k4 + 2], a16);
    a16 = fma((double)xv.w, u16[4 * k4 + 3], a16);
  }
  int nm = (n < NN) ? n : 0;
  double part = (a + ubd[c]) * (double)mw[(size_t)nm * 16 + c] + a16;
#pragma unroll
  for (int d = 1; d < 16; d <<= 1) part += __shfl_xor(part, d, 64);
  if (c == 0 && n < NN) s64[n] = (part + ubd[16]) * (1.0 / 1024.0);
}

// -------- keys + byte-0 LDS hist + done-counter pick (256-block grid-stride;
// NOTE: 1000-block one-shot measured ~116-123 us vs <82 at 256 blocks - keep 256)
__global__ void k_keysel(const int* __restrict__ ei, const float* __restrict__ ew,
                         const double* __restrict__ s64,
                         unsigned long long* __restrict__ keys,
                         unsigned* __restrict__ hist, SelState* st) {
  __shared__ unsigned h[256], suf[256];
  __shared__ int last;
  int tid = threadIdx.x;
  h[tid] = 0u;
  if (tid == 0) last = 0;
  __syncthreads();
  for (int e = blockIdx.x * 256 + tid; e < NE; e += gridDim.x * 256) {
    int d = ei[NE + e];
    double v = s64[d] * (double)ew[e];
    unsigned long long u = (unsigned long long)__double_as_longlong(v);
    u = (u & 0x8000000000000000ull) ? ~u : (u | 0x8000000000000000ull);
    keys[e] = u;
    atomicAdd(&h[(unsigned)(u >> 56)], 1u);
  }
  __syncthreads();
  if (h[tid]) atomicAdd(&hist[tid], h[tid]);
  __threadfence();
  __syncthreads();
  if (tid == 0) {
    if (atomicAdd(&st->done[0], 1u) == gridDim.x - 1) last = 1;
  }
  __syncthreads();
  if (!last) return;
  unsigned c = atomicAdd(&hist[tid], 0u);
  suf[tid] = c;
  __syncthreads();
  for (int d = 1; d < 256; d <<= 1) {
    unsigned v = (tid + d < 256) ? suf[tid + d] : 0u;
    __syncthreads();
    suf[tid] += v;
    __syncthreads();
  }
  unsigned r = st->r;
  unsigned exc = suf[tid] - c;
  if (exc < r && exc + c >= r) {
    st->prefix = (unsigned long long)tid;
    st->r = r - exc;
  }
}

// -------- byte-1 pass (LDS hist among byte0-matching keys) -> 16-bit prefix
__global__ void k_radix1(const unsigned long long* __restrict__ keys,
                         unsigned* __restrict__ hist, SelState* st) {
  __shared__ unsigned h[256], suf[256];
  __shared__ int last;
  int tid = threadIdx.x;
  h[tid] = 0u;
  if (tid == 0) last = 0;
  unsigned long long pref = st->prefix;
  __syncthreads();
  unsigned* hp = hist + 256;
  for (int e = blockIdx.x * 256 + tid; e < NE; e += gridDim.x * 256) {
    unsigned long long k = keys[e];
    if ((k >> 56) == pref)
      atomicAdd(&h[(unsigned)((k >> 48) & 255ull)], 1u);
  }
  __syncthreads();
  if (h[tid]) atomicAdd(&hp[tid], h[tid]);
  __threadfence();
  __syncthreads();
  if (tid == 0) {
    if (atomicAdd(&st->done[1], 1u) == gridDim.x - 1) last = 1;
  }
  __syncthreads();
  if (!last) return;
  unsigned c = atomicAdd(&hp[tid], 0u);
  suf[tid] = c;
  __syncthreads();
  for (int d = 1; d < 256; d <<= 1) {
    unsigned v = (tid + d < 256) ? suf[tid + d] : 0u;
    __syncthreads();
    suf[tid] += v;
    __syncthreads();
  }
  unsigned r = st->r;
  unsigned exc = suf[tid] - c;
  if (exc < r && exc + c >= r) {
    st->prefix = (st->prefix << 8) | (unsigned long long)tid;
    st->r = r - exc;
  }
}

// ------- ballot selection bitmask (>P16) + candidate collect; tail resolves
__global__ void k_candsel(const unsigned long long* __restrict__ keys,
                          SelState* st,
                          unsigned long long* __restrict__ flags,
                          unsigned long long* __restrict__ candk, int* __restrict__ cande) {
  __shared__ unsigned h[256], suf[256];
  __shared__ unsigned long long spref;
  __shared__ unsigned sr;
  __shared__ int last;
  int tid = threadIdx.x;
  if (tid == 0) last = 0;
  unsigned P16 = (unsigned)st->prefix;
  for (int e = blockIdx.x * 256 + tid; e < NE; e += gridDim.x * 256) {
    unsigned long long k = keys[e];
    unsigned t16 = (unsigned)(k >> 48);
    unsigned long long bal = __ballot(t16 > P16);
    if ((tid & 63) == 0) flags[e >> 6] = bal;   // lane0's e is 64-aligned
    if (t16 == P16) {
      unsigned pos = atomicAdd(&st->tiec, 1u);
      if (pos < CANDCAP) { candk[pos] = k; cande[pos] = e; }
    }
  }
  __threadfence();
  __syncthreads();
  if (tid == 0) {
    if (atomicAdd(&st->done[2], 1u) == gridDim.x - 1) last = 1;
  }
  __syncthreads();
  if (!last) return;
  // ---- tail: resolve bytes 2..7 among candidates
  unsigned C = atomicAdd(&st->tiec, 0u); if (C > CANDCAP) C = CANDCAP;
  if (tid == 0) { spref = (unsigned long long)P16; sr = st->r; }
  __syncthreads();
  for (int p = 2; p < 8; ++p) {
    h[tid] = 0u;
    __syncthreads();
    int shift = 56 - 8 * p;
    unsigned long long pf = spref;
    unsigned r = sr;
    for (unsigned i = tid; i < C; i += 256) {
      unsigned long long k = candk[i];
      if ((k >> (shift + 8)) == pf) atomicAdd(&h[(unsigned)((k >> shift) & 255ull)], 1u);
    }
    __syncthreads();
    suf[tid] = h[tid];
    __syncthreads();
    for (int d = 1; d < 256; d <<= 1) {
      unsigned v = (tid + d < 256) ? suf[tid + d] : 0u;
      __syncthreads();
      suf[tid] += v;
      __syncthreads();
    }
    unsigned exc = suf[tid] - h[tid];
    if (exc < r && exc + h[tid] >= r) {
      spref = (pf << 8) | (unsigned long long)tid;
      sr = r - exc;
    }
    __syncthreads();
  }
  unsigned long long T = spref;
  unsigned needed = sr;
  // set flag bits for candidates: >T outright; ==T lowest-index ties
  for (unsigned i = tid; i < C; i += 256) {
    unsigned long long k = candk[i];
    int e2 = cande[i];
    bool take = false;
    if (k > T) take = true;
    else if (k == T) {
      unsigned rank = 0;
      for (unsigned q = 0; q < C; ++q)
        rank += (candk[q] == T && cande[q] < e2) ? 1u : 0u;
      take = (rank < needed);
    }
    if (take) atomicOr(&flags[e2 >> 6], 1ull << (e2 & 63));
  }
}

// ------- per-chunk LDS histogram (packed u16, plain global stores)
__global__ __launch_bounds__(256) void k_count1(const int* __restrict__ ei,
                                                const unsigned long long* __restrict__ flags,
                                                unsigned* __restrict__ hpart) {
  __shared__ unsigned hp[HPW];
  int tid = threadIdx.x;
  for (int i = tid; i < HPW; i += 256) hp[i] = 0u;
  __syncthreads();
  int base = blockIdx.x * ECH;
  int lim = base + ECH; if (lim > NE) lim = NE;
  for (int k0 = 0; k0 < RND; k0 += 4) {
    int nn[4]; bool tk[4];
#pragma unroll
    for (int q = 0; q < 4; ++q) {
      int e = base + tid + (k0 + q) * 256;
      bool valid = e < lim;
      unsigned long long w = valid ? flags[e >> 6] : 0ull;
      nn[q] = valid ? ei[e] : 0;
      tk[q] = valid && ((w >> (e & 63)) & 1ull);
    }
#pragma unroll
    for (int q = 0; q < 4; ++q)
      if (tk[q]) atomicAdd(&hp[nn[q] >> 1], 1u << ((nn[q] & 1) * 16));
  }
  __syncthreads();
  unsigned* dst = hpart + (size_t)blockIdx.x * HPW;
  for (int i = tid; i < HPW; i += 256) dst[i] = hp[i];
}

// ------- per-node chunk prefix + cnt + block-sum; tail computes bbase/total
__global__ void k_prefA(const unsigned* __restrict__ hpart,
                        unsigned short* __restrict__ hoffl,
                        unsigned* __restrict__ cnt, unsigned* __restrict__ bsum,
                        unsigned* __restrict__ bbase, unsigned* __restrict__ offar,
                        SelState* st) {
  __shared__ unsigned sd[256];
  __shared__ int last;
  int tid = threadIdx.x;
  if (tid == 0) last = 0;
  int n = blockIdx.x * 256 + tid;
  unsigned tot = 0u;
  if (n < NN) {
    int half = (n & 1) * 16;
    int wi = n >> 1;
#pragma unroll 4
    for (int b = 0; b < CH; ++b) {
      hoffl[(size_t)b * NN + n] = (unsigned short)tot;
      tot += (hpart[(size_t)b * HPW + wi] >> half) & 0xFFFFu;
    }
    cnt[n] = tot;
  }
  sd[tid] = (n < NN) ? tot : 0u;
  __syncthreads();
  for (int s = 128; s > 0; s >>= 1) {
    if (tid < s) sd[tid] += sd[tid + s];
    __syncthreads();
  }
  if (tid == 0) bsum[blockIdx.x] = sd[0];
  __threadfence();
  __syncthreads();
  if (tid == 0) {
    if (atomicAdd(&st->done[3], 1u) == gridDim.x - 1) last = 1;
  }
  __syncthreads();
  if (!last) return;
  unsigned v = (tid < NB) ? bsum[tid] : 0u;
  sd[tid] = v;
  __syncthreads();
  for (int d = 1; d < 256; d <<= 1) {
    unsigned u = (tid >= d) ? sd[tid - d] : 0u;
    __syncthreads();
    sd[tid] += u;
    __syncthreads();
  }
  if (tid < NB) bbase[tid] = sd[tid] - v;
  if (tid == NB - 1) offar[NN] = sd[tid];
}

// ------- offar via intra-block scan
__global__ void k_prefB(const unsigned* __restrict__ cnt, const unsigned* __restrict__ bbase,
                        unsigned* __restrict__ offar) {
  __shared__ unsigned sd[256];
  int tid = threadIdx.x;
  int n = blockIdx.x * 256 + tid;
  unsigned v = (n < NN) ? cnt[n] : 0u;
  sd[tid] = v;
  __syncthreads();
  for (int d = 1; d < 256; d <<= 1) {
    unsigned u = (tid >= d) ? sd[tid - d] : 0u;
    __syncthreads();
    sd[tid] += u;
    __syncthreads();
  }
  if (n < NN) offar[n] = bbase[blockIdx.x] + sd[tid] - v;
}

// ------- per-chunk scatter with LDS relative cursors (no global atomics)
__global__ __launch_bounds__(256) void k_scatterC(const int* __restrict__ ei,
                                                  const unsigned long long* __restrict__ flags,
                                                  const unsigned* __restrict__ offar,
                                                  const unsigned short* __restrict__ hoffl,
                                                  int* __restrict__ csr) {
  __shared__ unsigned rel[HPW];
  int tid = threadIdx.x;
  for (int i = tid; i < HPW; i += 256) rel[i] = 0u;
  __syncthreads();
  int base = blockIdx.x * ECH;
  int lim = base + ECH; if (lim > NE) lim = NE;
  const unsigned short* hl = hoffl + (size_t)blockIdx.x * NN;
  for (int k0 = 0; k0 < RND; k0 += 4) {
    int nn[4]; bool tk[4]; unsigned hb4[4];
#pragma unroll
    for (int q = 0; q < 4; ++q) {
      int e = base + tid + (k0 + q) * 256;
      bool valid = e < lim;
      unsigned long long w = valid ? flags[e >> 6] : 0ull;
      tk[q] = valid && ((w >> (e & 63)) & 1ull);
      nn[q] = valid ? ei[e] : 0;
      hb4[q] = tk[q] ? (offar[nn[q]] + (unsigned)hl[nn[q]]) : 0u;
    }
#pragma unroll
    for (int q = 0; q < 4; ++q) {
      if (tk[q]) {
        int half = (nn[q] & 1) * 16;
        unsigned old = atomicAdd(&rel[nn[q] >> 1], 1u << half);
        unsigned r = (old >> half) & 0xFFFFu;
        unsigned pos = hb4[q] + r;
        if (pos < KSEL) csr[pos] = base + tid + (k0 + q) * 256;
      }
    }
  }
}

// --------- per-node softmax + weighted gather: ONE WAVE PER NODE, no barriers
__global__ __launch_bounds__(256) void k_out(
    const int* __restrict__ ei, const float* __restrict__ ew,
    const float* __restrict__ beta, const float* __restrict__ V,
    const unsigned* __restrict__ offar, const int* __restrict__ csr,
    float* __restrict__ out) {
  int n = (blockIdx.x * 256 + threadIdx.x) >> 6;   // global wave id = node
  int lane = threadIdx.x & 63;
  if (n >= NN) return;
  unsigned beg = offar[n], end = offar[n + 1];
  if (end > (unsigned)KSEL) end = KSEL;
  if (beg > end) beg = end;
  float mval = -INFINITY, den = 0.f;   // softmax state for t = lane&31 (dup'd in hi half)
  float acc0 = 0.f, acc1 = 0.f;        // channels lane, lane+64
  int t0 = lane >> 2, t1 = 16 + (lane >> 2);
  int tl = lane & 31;

  for (unsigned cb = beg; cb < end; cb += 64u) {
    unsigned ce = end - cb; if (ce > 64u) ce = 64u;
    int d_l = 0; float w_l = 0.f;
    if (lane < (int)ce) {
      int e = csr[cb + lane];
      d_l = ei[NE + e];
      w_l = ew[e];
    }
    for (int i = 0; i < (int)ce; ++i) {
      int d = __shfl(d_l, i, 64);
      float wv = __shfl(w_l, i, 64);
      float b = beta[(size_t)d * NSTEP + tl] * wv;
      float mnew = fmaxf(mval, b);
      float sc = expf(mval - mnew);    // 0 when mval was -inf
      float gg = expf(b - mnew);
      den = den * sc + gg;
      mval = mnew;
      float sc0 = __shfl(sc, t0, 64), g0 = __shfl(gg, t0, 64);
      float sc1 = __shfl(sc, t1, 64), g1 = __shfl(gg, t1, 64);
      const float* vr = V + (size_t)d * OC;
      acc0 = acc0 * sc0 + vr[lane] * g0;
      acc1 = acc1 * sc1 + vr[64 + lane] * g1;
    }
  }
  float den0 = __shfl(den, t0, 64);
  float den1 = __shfl(den, t1, 64);
  out[(size_t)n * OC + lane]      = (den0 > 0.f) ? acc0 / den0 : 0.f;
  out[(size_t)n * OC + 64 + lane] = (den1 > 0.f) ? acc1 / den1 : 0.f;
}

// --------------------------------------------------------------------- host
extern "C" void kernel_launch(void* const* d_in, const int* in_sizes, int n_in,
                              void* d_out, int out_size, void* d_ws, size_t ws_size,
                              hipStream_t stream) {
  const float* x     = (const float*)d_in[0];
  const float* p_t   = (const float*)d_in[1];
  const int*   ei    = (const int*)d_in[2];
  const float* ew    = (const float*)d_in[3];
  const float* lin_w = (const float*)d_in[4];
  const float* lin_b = (const float*)d_in[5];
  const float* inc_w = (const float*)d_in[6];
  const float* inc_b = (const float*)d_in[7];
  const float* mw    = (const float*)d_in[8];
  float* out = (float*)d_out;

  char* w = (char*)d_ws;
  size_t off = 0;
  auto alloc = [&](size_t b) -> void* {
    void* p = w + off;
    off += (b + 511) & ~(size_t)511;
    return p;
  };
  float*  Wq    = (float*)alloc((size_t)33 * NQCOL * 4 * 4);
  double* Ud    = (double*)alloc((size_t)17 * IC * 8);
  double* ubd   = (double*)alloc(17 * 8);
  float*  beta  = (float*)alloc((size_t)NN * NSTEP * 4);
  double* s64   = (double*)alloc((size_t)NN * 8);
  float*  V     = (float*)alloc((size_t)NN * OC * 4);
  unsigned long long* keys  = (unsigned long long*)alloc((size_t)NE * 8);
  unsigned long long* flags = (unsigned long long*)alloc((size_t)(NE / 64) * 8);
  unsigned long long* candk = (unsigned long long*)alloc((size_t)CANDCAP * 8);
  int*      cande  = (int*)alloc((size_t)CANDCAP * 4);
  unsigned* hpart  = (unsigned*)alloc((size_t)CH * HPW * 4);
  unsigned short* hoffl = (unsigned short*)alloc((size_t)CH * NN * 2);
  unsigned* cnt    = (unsigned*)alloc((size_t)NN * 4);
  unsigned* offar  = (unsigned*)alloc((size_t)(NN + 1) * 4);
  int*      csr    = (int*)alloc((size_t)KSEL * 4);
  unsigned* hist   = (unsigned*)alloc(512 * 4);
  unsigned* bsum   = (unsigned*)alloc(NB * 4);
  unsigned* bbase  = (unsigned*)alloc(NB * 4);
  SelState* st     = (SelState*)alloc(sizeof(SelState));
  if (off > ws_size) return;

  int init_threads = 33 * NQCOL + 17 * IC + 17 + 512 + 1;
  k_init<<<(init_threads + 255) / 256, 256, 0, stream>>>(p_t, lin_w, lin_b, inc_w, inc_b,
                                                         Wq, Ud, ubd, hist, st);
  k_node<<<1600, 256, 0, stream>>>(x, mw, Wq, beta, V);   // 40 chunks x 40 blocks
  k_s64<<<(NN + 15) / 16, 256, 0, stream>>>(x, mw, Ud, ubd, s64);
  k_keysel<<<256, 256, 0, stream>>>(ei, ew, s64, keys, hist, st);
  k_radix1<<<256, 256, 0, stream>>>(keys, hist, st);
  k_candsel<<<256, 256, 0, stream>>>(keys, st, flags, candk, cande);
  k_count1<<<CH, 256, 0, stream>>>(ei, flags, hpart);
  k_prefA<<<NB, 256, 0, stream>>>(hpart, hoffl, cnt, bsum, bbase, offar, st);
  k_prefB<<<NB, 256, 0, stream>>>(cnt, bbase, offar);
  k_scatterC<<<CH, 256, 0, stream>>>(ei, flags, offar, hoffl, csr);
  k_out<<<(NN * 64 + 255) / 256, 256, 0, stream>>>(ei, ew, beta, V, offar, csr, out);
}